// Round 6
// baseline (8610.591 us; speedup 1.0000x reference)
//
#include <hip/hip_runtime.h>

typedef _Float16 f16;
typedef _Float16 f16x8 __attribute__((ext_vector_type(8)));
typedef float f32x4 __attribute__((ext_vector_type(4)));
typedef unsigned short ushort_t;
typedef unsigned int uint_t;

// ---------------------------------------------------------------------------
// PoseConvLSTM persistent kernel, 129 phases, grid 512 (2 blocks/CU).
// Phase ph: layer1[t=ph] (even channel-slices) ∥ layer2[t=ph-1] (all).
// A (weights) split-f16 hi+lo (2 MFMA/product); B (states) f16 hi only.
//
// Exchange buffers: TILE-MAJOR [tile(64)][pair(C/2)][pix(64)] uints
// (uint = f16 pair of 2 adjacent channels) so producer stores are 64B-dense
// wave-contiguous write-through transactions (fix for R5's 14 GB WRITE_SIZE).
//   in2[par]: 48 pairs: 0-15 = h1[t], 16-47 = h2prev
//   in1[par]: 24 pairs: 0-15 = h1prev, 16-17 = x[t] (x2 paired with 0), 18-23 = 0
// All cross-block data via relaxed agent-scope atomics (write-through /
// L2-bypass; no wbl2/inv). c-states live in registers. Barrier: sharded
// scan + 8 release-flag sectors.
// d_out (floats): pose[768] | h1[131072] | c1[131072] | h2[262144] | c2[262144]
// ---------------------------------------------------------------------------

#define I1U 98304    // 64*24*64 uints per parity
#define I2U 196608   // 64*48*64
#define EXU 589824   // 2*(I1U+I2U)
#define WP1U 589824  // uint offset of wp1
#define WP2U 663552  // + 73728
#define BARU 884736  // uint offset of barrier region
#define NPH 129

__device__ __forceinline__ float sigm(float x) { return 1.0f / (1.0f + __expf(-x)); }
__device__ __forceinline__ ushort_t f2u(f16 v) { return __builtin_bit_cast(ushort_t, v); }
__device__ __forceinline__ f16x8 u2f(uint4 v) { return __builtin_bit_cast(f16x8, v); }
__device__ __forceinline__ uint_t loadc(const uint_t* p) {
  return __hip_atomic_load(p, __ATOMIC_RELAXED, __HIP_MEMORY_SCOPE_AGENT);
}
__device__ __forceinline__ void storec(uint_t* p, uint_t v) {
  __hip_atomic_store(p, v, __ATOMIC_RELAXED, __HIP_MEMORY_SCOPE_AGENT);
}

// ---- init: pack weights (hi/lo frag order); pose=fc_b; stage x[0] ----
__global__ __launch_bounds__(256) void pack_kernel(const float* __restrict__ w1,
                                                   const float* __restrict__ w2,
                                                   const float* __restrict__ fcb,
                                                   const float* __restrict__ x0,
                                                   float* __restrict__ pose,
                                                   ushort_t* __restrict__ wp1,
                                                   ushort_t* __restrict__ wp2,
                                                   uint_t* __restrict__ i1a) {
  int i = blockIdx.x * 256 + threadIdx.x;
  if (i < 55296) {  // wp2
    int lane = i & 63;
    int r0 = i >> 6;
    int hl = r0 & 1;
    int f = r0 >> 1;  // (mb*27+s)*8+mt
    int mt = f & 7;
    int sm = f >> 3;
    int s = sm % 27, mb = sm / 27;
    int m = mt * 16 + (lane & 15);
    int rg = mb * 128 + m;
    int h = rg >> 2, G = rg & 3;
    int orow = G * 64 + h;
    int tap = s / 3, cb = (s % 3) * 32;
    int cq = cb + (lane >> 4) * 8;
    for (int j = 0; j < 8; ++j) {
      float v = w2[(orow * 96 + cq + j) * 9 + tap];
      f16 vh = (f16)v;
      f16 vl = (f16)(v - (float)vh);
      wp2[(f * 2 + hl) * 512 + lane * 8 + j] = f2u(hl ? vl : vh);
    }
    return;
  }
  i -= 55296;
  if (i < 18432) {  // wp1: c<32 -> w1 ch c+3 (h1), c32-34 -> w1 ch c-32 (x), else 0
    int lane = i & 63;
    int r0 = i >> 6;
    int hl = r0 & 1;
    int f = r0 >> 1;  // (mb*18+s)*4+mt
    int mt = f & 3;
    int sm = f >> 2;
    int s = sm % 18, mb = sm / 18;
    int m = mt * 16 + (lane & 15);
    int rg = mb * 64 + m;
    int h = rg >> 2, G = rg & 3;
    int orow = G * 32 + h;
    int tap = s >> 1, cb = (s & 1) * 32;
    int cq = cb + (lane >> 4) * 8;
    for (int j = 0; j < 8; ++j) {
      int c = cq + j;
      float v = 0.f;
      if (c < 32) v = w1[(orow * 35 + (c + 3)) * 9 + tap];
      else if (c < 35) v = w1[(orow * 35 + (c - 32)) * 9 + tap];
      f16 vh = (f16)v;
      f16 vl = (f16)(v - (float)vh);
      wp1[(f * 2 + hl) * 512 + lane * 8 + j] = f2u(hl ? vl : vh);
    }
    return;
  }
  i -= 18432;
  if (i < 768) {
    pose[i] = fcb[i % 6];
    return;
  }
  i -= 768;
  if (i < 4096) {  // x[0] -> in1 parity0, tile-major pairs 16,17
    int y = i >> 6, x = i & 63;
    float v0 = x0[i], v1 = x0[4096 + i], v2 = x0[8192 + i];
    int tile = (y >> 3) * 8 + (x >> 3);
    int pit = (y & 7) * 8 + (x & 7);
    i1a[(tile * 24 + 16) * 64 + pit] = (uint_t)f2u((f16)v0) | ((uint_t)f2u((f16)v1) << 16);
    i1a[(tile * 24 + 17) * 64 + pit] = (uint_t)f2u((f16)v2);
  }
}

#define MFMA(a, b, c) __builtin_amdgcn_mfma_f32_16x16x32_f16((a), (b), (c), 0, 0, 0)

__global__ __launch_bounds__(256, 2) void persist(
    const float* __restrict__ input, const ushort_t* __restrict__ wp1,
    const ushort_t* __restrict__ wp2, const float* __restrict__ b1g,
    const float* __restrict__ b2g, const float* __restrict__ fcw, float* __restrict__ pose,
    float* __restrict__ h1o, float* __restrict__ c1o, float* __restrict__ h2o,
    float* __restrict__ c2o, uint_t* i1x, uint_t* i1y, uint_t* i2x, uint_t* i2y,
    uint_t* bars) {
  __shared__ __align__(16) ushort_t BH2[100 * 104];  // [pos][96ch + 8 pad]
  __shared__ __align__(16) ushort_t BH1[100 * 72];   // [pos][64ch + 8 pad]
  __shared__ float zs[8 * 4 * 64];
  __shared__ float red[4][6];

  const int tid = threadIdx.x, blk = blockIdx.x;
  const int lane = tid & 63, w = tid >> 6;
  const int q = lane >> 4, nl = lane & 15, py = nl >> 3, px = nl & 7;
  const int mbx = blk & 7;
  const int nc = blk >> 3;
  const int Y0 = (nc >> 3) * 8, X0 = (nc & 7) * 8;
  const int mt = w & 1, kh = w >> 1;
  const bool l1act = (mbx & 1) == 0;
  const int mbh = mbx >> 1;

  uint_t* i1[2] = {i1x, i1y};
  uint_t* i2[2] = {i2x, i2y};
  uint_t* uBH2 = (uint_t*)BH2;
  uint_t* uBH1 = (uint_t*)BH1;

  // A-frag base pointers
  const int mt2p = mbx * 2 + mt;
  const int mb2 = mt2p >> 3, mtl2 = mt2p & 7;
  const int mt1p = mbh * 2 + mt;
  const int mb1 = mt1p >> 2, mtl1 = mt1p & 3;
  const int s0_2 = kh ? 14 : 0, s1_2 = kh ? 27 : 14;
  const int s0_1 = kh ? 9 : 0, s1_1 = kh ? 18 : 9;
  const ushort_t* aB2 = wp2 + ((size_t)(mb2 * 27 + s0_2) * 8 + mtl2) * 1024 + lane * 8;
  const ushort_t* aB1 = wp1 + ((size_t)(mb1 * 18 + s0_1) * 4 + mtl1) * 1024 + lane * 8;

  int bO2[4], bO1[4];
#pragma unroll
  for (int nt = 0; nt < 4; ++nt) {
    bO2[nt] = ((nt * 2 + py) * 10 + px) * 104 + q * 8;
    bO1[nt] = ((nt * 2 + py) * 10 + px) * 72 + q * 8;
  }

  // ---- precompute phase-invariant staging offsets (tile-major) ----
  int gO2[19], lO2[19];
  uint_t vm2 = 0;
#pragma unroll
  for (int k = 0; k < 19; ++k) {
    int i = tid + k * 256;
    if (i > 4799) i = 4799;
    int pair = i / 100, pos = i - pair * 100;
    int hy = pos / 10, hx = pos - hy * 10;
    int gy = Y0 + hy - 1, gx = X0 + hx - 1;
    if ((unsigned)gy < 64u && (unsigned)gx < 64u) vm2 |= (1u << k);
    int tile = ((gy & 63) >> 3) * 8 + ((gx & 63) >> 3);
    int pit = ((gy & 7) << 3) + (gx & 7);
    gO2[k] = (tile * 48 + pair) * 64 + pit;
    lO2[k] = pos * 52 + pair;
  }
  int gO1[8], lO1[8];
  uint_t vm1 = 0;
#pragma unroll
  for (int k = 0; k < 8; ++k) {
    int i = tid + k * 256;
    if (i > 1799) i = 1799;
    int pair = i / 100, pos = i - pair * 100;
    int hy = pos / 10, hx = pos - hy * 10;
    int gy = Y0 + hy - 1, gx = X0 + hx - 1;
    if ((unsigned)gy < 64u && (unsigned)gx < 64u) vm1 |= (1u << k);
    int tile = ((gy & 63) >> 3) * 8 + ((gx & 63) >> 3);
    int pit = ((gy & 7) << 3) + (gx & 7);
    gO1[k] = (tile * 24 + pair) * 64 + pit;
    lO1[k] = pos * 36 + pair;
  }
  // one-time zero of BH1 channels 36..63 (uints 18..31; never overwritten)
  for (int z = tid; z < 1400; z += 256) {
    int pos = z / 14, u = 18 + (z - (z / 14) * 14);
    uBH1[pos * 36 + u] = 0u;
  }

  // preload biases + fcw (cell ownership phase-invariant)
  const int h2ch = mbx * 8 + mt * 4 + q;
  const int h1ch = mbh * 8 + mt * 4 + q;
  float b2r[4], b1r[4], fwr[2][6];
  int cidx2[2], cidx1[2];
#pragma unroll
  for (int G = 0; G < 4; ++G) {
    b2r[G] = b2g[G * 64 + h2ch];
    b1r[G] = b1g[G * 32 + h1ch];
  }
#pragma unroll
  for (int j = 0; j < 2; ++j) {
    int nt = kh * 2 + j;
    int y = Y0 + nt * 2 + py, x = X0 + px;
    cidx2[j] = h2ch * 4096 + y * 64 + x;
    cidx1[j] = h1ch * 4096 + y * 64 + x;
#pragma unroll
    for (int jj = 0; jj < 6; ++jj) fwr[j][jj] = fcw[jj * 262144 + cidx2[j]];
  }

  float c2r[2] = {0.f, 0.f}, c1r[2] = {0.f, 0.f};

  for (int ph = 0; ph < NPH; ++ph) {
    const int t1 = ph, t2 = ph - 1;
    const int p = ph & 1, pn = p ^ 1;
    const bool doL2 = (t2 >= 0), doL1 = l1act && (t1 < 128);

    // ---- batched staging (all loads in flight, then LDS writes) ----
    {
      const uint_t* s2 = i2[pn];
      uint_t v[19];
#pragma unroll
      for (int k = 0; k < 19; ++k) v[k] = loadc(s2 + gO2[k]);
#pragma unroll
      for (int k = 0; k < 19; ++k) uBH2[lO2[k]] = ((vm2 >> k) & 1) ? v[k] : 0u;
      if (l1act) {
        const uint_t* s1 = i1[p];
        uint_t u[8];
#pragma unroll
        for (int k = 0; k < 8; ++k) u[k] = loadc(s1 + gO1[k]);
#pragma unroll
        for (int k = 0; k < 8; ++k) uBH1[lO1[k]] = ((vm1 >> k) & 1) ? u[k] : 0u;
      }
    }
    __syncthreads();

    // ---- layer 2 K-loop: wave = (mt, kh), 4 n-tiles, K-half ----
    f32x4 acc[4] = {{0, 0, 0, 0}, {0, 0, 0, 0}, {0, 0, 0, 0}, {0, 0, 0, 0}};
    if (doL2) {
      uint4 Ahb[2], Alb[2], Bb[2][4];
      Ahb[0] = *(const uint4*)(aB2);
      Alb[0] = *(const uint4*)(aB2 + 512);
      Ahb[1] = *(const uint4*)(aB2 + 8192);
      Alb[1] = *(const uint4*)(aB2 + 8704);
      {
        int cc = s0_2 % 3, tt = s0_2 / 3;
        int d = (tt / 3) * 1040 + (tt % 3) * 104 + cc * 32;
#pragma unroll
        for (int nt = 0; nt < 4; ++nt) Bb[0][nt] = *(const uint4*)(&BH2[bO2[nt] + d]);
      }
      for (int s = s0_2, i = 0; s < s1_2; ++s, ++i) {
        uint4 ah = Ahb[i & 1], al = Alb[i & 1];
        uint4 b0 = Bb[i & 1][0], b1 = Bb[i & 1][1], b2 = Bb[i & 1][2], b3 = Bb[i & 1][3];
        if (s + 2 < s1_2) {
          Ahb[i & 1] = *(const uint4*)(aB2 + (size_t)(i + 2) * 8192);
          Alb[i & 1] = *(const uint4*)(aB2 + (size_t)(i + 2) * 8192 + 512);
        }
        if (s + 1 < s1_2) {
          int sn = s + 1;
          int cc = sn % 3, tt = sn / 3;
          int d = (tt / 3) * 1040 + (tt % 3) * 104 + cc * 32;
#pragma unroll
          for (int nt = 0; nt < 4; ++nt) Bb[(i + 1) & 1][nt] = *(const uint4*)(&BH2[bO2[nt] + d]);
        }
        f16x8 A_h = u2f(ah), A_l = u2f(al);
        f16x8 B0 = u2f(b0), B1 = u2f(b1), B2 = u2f(b2), B3 = u2f(b3);
        acc[0] = MFMA(A_h, B0, acc[0]); acc[0] = MFMA(A_l, B0, acc[0]);
        acc[1] = MFMA(A_h, B1, acc[1]); acc[1] = MFMA(A_l, B1, acc[1]);
        acc[2] = MFMA(A_h, B2, acc[2]); acc[2] = MFMA(A_l, B2, acc[2]);
        acc[3] = MFMA(A_h, B3, acc[3]); acc[3] = MFMA(A_l, B3, acc[3]);
      }
      int pub = (kh ^ 1) * 2;
#pragma unroll
      for (int j = 0; j < 2; ++j) {
        int tile = mt * 4 + pub + j;
#pragma unroll
        for (int i = 0; i < 4; ++i) zs[(tile * 4 + i) * 64 + lane] = acc[pub + j][i];
      }
    }
    __syncthreads();

    // ---- layer 2 merge + epilogue ----
    if (doL2) {
      uint_t* dst = i2[p];
      float p6[6] = {0, 0, 0, 0, 0, 0};
#pragma unroll
      for (int j = 0; j < 2; ++j) {
        int nt = kh * 2 + j;
        int tile = mt * 4 + nt;
        f32x4 a = acc[nt];
#pragma unroll
        for (int i = 0; i < 4; ++i) a[i] += zs[(tile * 4 + i) * 64 + lane];
        float zi = a[0] + b2r[0], zf = a[1] + b2r[1], zo = a[2] + b2r[2], zg = a[3] + b2r[3];
        float cn = sigm(zf) * c2r[j] + sigm(zi) * tanhf(zg);
        float hn = sigm(zo) * tanhf(cn);
        c2r[j] = cn;
#pragma unroll
        for (int jj = 0; jj < 6; ++jj) p6[jj] += hn * fwr[j][jj];
        if (t2 < 127) {
          ushort_t hv = f2u((f16)hn);
          uint_t pw = (uint_t)__shfl_xor((int)(uint_t)hv, 16, 64);
          if ((q & 1) == 0) {  // dense 64B run: 16 lanes x consecutive pix
            int d = (nc * 48 + 16 + (h2ch >> 1)) * 64 + nt * 16 + nl;
            storec(dst + d, (uint_t)hv | (pw << 16));
          }
        } else {
          c2o[cidx2[j]] = cn;
          h2o[cidx2[j]] = hn;
        }
      }
#pragma unroll
      for (int jj = 0; jj < 6; ++jj)
#pragma unroll
        for (int off = 32; off; off >>= 1) p6[jj] += __shfl_xor(p6[jj], off, 64);
      if (lane == 0)
#pragma unroll
        for (int jj = 0; jj < 6; ++jj) red[w][jj] = p6[jj];
    }

    // ---- layer 1 K-loop ----
    f32x4 ac1[4] = {{0, 0, 0, 0}, {0, 0, 0, 0}, {0, 0, 0, 0}, {0, 0, 0, 0}};
    if (doL1) {
      uint4 Ahb[2], Alb[2], Bb[2][4];
      Ahb[0] = *(const uint4*)(aB1);
      Alb[0] = *(const uint4*)(aB1 + 512);
      Ahb[1] = *(const uint4*)(aB1 + 4096);
      Alb[1] = *(const uint4*)(aB1 + 4608);
      {
        int cc = s0_1 & 1, tap = s0_1 >> 1;
        int d = (tap / 3) * 720 + (tap % 3) * 72 + cc * 32;
#pragma unroll
        for (int nt = 0; nt < 4; ++nt) Bb[0][nt] = *(const uint4*)(&BH1[bO1[nt] + d]);
      }
      for (int s = s0_1, i = 0; s < s1_1; ++s, ++i) {
        uint4 ah = Ahb[i & 1], al = Alb[i & 1];
        uint4 b0 = Bb[i & 1][0], b1 = Bb[i & 1][1], b2 = Bb[i & 1][2], b3 = Bb[i & 1][3];
        if (s + 2 < s1_1) {
          Ahb[i & 1] = *(const uint4*)(aB1 + (size_t)(i + 2) * 4096);
          Alb[i & 1] = *(const uint4*)(aB1 + (size_t)(i + 2) * 4096 + 512);
        }
        if (s + 1 < s1_1) {
          int sn = s + 1;
          int cc = sn & 1, tap = sn >> 1;
          int d = (tap / 3) * 720 + (tap % 3) * 72 + cc * 32;
#pragma unroll
          for (int nt = 0; nt < 4; ++nt) Bb[(i + 1) & 1][nt] = *(const uint4*)(&BH1[bO1[nt] + d]);
        }
        f16x8 A_h = u2f(ah), A_l = u2f(al);
        f16x8 B0 = u2f(b0), B1 = u2f(b1), B2 = u2f(b2), B3 = u2f(b3);
        ac1[0] = MFMA(A_h, B0, ac1[0]); ac1[0] = MFMA(A_l, B0, ac1[0]);
        ac1[1] = MFMA(A_h, B1, ac1[1]); ac1[1] = MFMA(A_l, B1, ac1[1]);
        ac1[2] = MFMA(A_h, B2, ac1[2]); ac1[2] = MFMA(A_l, B2, ac1[2]);
        ac1[3] = MFMA(A_h, B3, ac1[3]); ac1[3] = MFMA(A_l, B3, ac1[3]);
      }
    }
    __syncthreads();  // zs reuse fence
    if (doL1) {
      int pub = (kh ^ 1) * 2;
#pragma unroll
      for (int j = 0; j < 2; ++j) {
        int tile = mt * 4 + pub + j;
#pragma unroll
        for (int i = 0; i < 4; ++i) zs[(tile * 4 + i) * 64 + lane] = ac1[pub + j][i];
      }
    }
    if (mbx == 1 && t1 < 127 && tid < 64) {  // stage x[t+1] -> in1[pn] pairs 16,17
      const float* xn = input + (size_t)(t1 + 1) * 12288;
      int y = Y0 + (tid >> 3), x = X0 + (tid & 7);
      int gi = y * 64 + x;
      float v0 = xn[gi], v1 = xn[4096 + gi], v2 = xn[8192 + gi];
      uint_t* d1 = i1[pn];
      storec(d1 + (nc * 24 + 16) * 64 + tid, (uint_t)f2u((f16)v0) | ((uint_t)f2u((f16)v1) << 16));
      storec(d1 + (nc * 24 + 17) * 64 + tid, (uint_t)f2u((f16)v2));
    }
    __syncthreads();
    if (doL1) {
      uint_t* d2 = i2[p];
      uint_t* d1 = i1[pn];
#pragma unroll
      for (int j = 0; j < 2; ++j) {
        int nt = kh * 2 + j;
        int tile = mt * 4 + nt;
        f32x4 a = ac1[nt];
#pragma unroll
        for (int i = 0; i < 4; ++i) a[i] += zs[(tile * 4 + i) * 64 + lane];
        float zi = a[0] + b1r[0], zf = a[1] + b1r[1], zo = a[2] + b1r[2], zg = a[3] + b1r[3];
        float cn = sigm(zf) * c1r[j] + sigm(zi) * tanhf(zg);
        float hn = sigm(zo) * tanhf(cn);
        c1r[j] = cn;
        ushort_t hv = f2u((f16)hn);
        uint_t pw = (uint_t)__shfl_xor((int)(uint_t)hv, 16, 64);
        if ((q & 1) == 0) {
          uint_t wv = (uint_t)hv | (pw << 16);
          int pix = nt * 16 + nl;
          storec(d2 + (nc * 48 + (h1ch >> 1)) * 64 + pix, wv);  // h1 -> in2[p]
          if (t1 < 127) storec(d1 + (nc * 24 + (h1ch >> 1)) * 64 + pix, wv);
        }
        if (t1 == 127) {
          c1o[cidx1[j]] = cn;
          h1o[cidx1[j]] = hn;
        }
      }
    }

    // ---- drain, pose, sharded grid barrier ----
    asm volatile("s_waitcnt vmcnt(0)" ::: "memory");
    __syncthreads();
    if (doL2 && tid < 6)
      atomicAdd(pose + t2 * 6 + tid, red[0][tid] + red[1][tid] + red[2][tid] + red[3][tid]);
    if (ph + 1 < NPH) {
      const uint_t gen = (uint_t)(ph + 1);
      const int g = blk >> 6;
      if (tid == 0) storec(bars + blk, gen);
      if ((blk & 63) == 0 && w == 0) {  // group scanner: 64 slots = 4 sectors
        for (;;) {
          bool ok = loadc(bars + g * 64 + lane) >= gen;
          if (__all(ok)) break;
          __builtin_amdgcn_s_sleep(2);
        }
        if (lane == 0) storec(bars + 512 + g * 16, gen);
      }
      if (blk == 0 && w == 1) {  // root: gather 8 group flags, fan out releases
        for (;;) {
          bool ok = (lane >= 8) || (loadc(bars + 512 + lane * 16) >= gen);
          if (__all(ok)) break;
          __builtin_amdgcn_s_sleep(2);
        }
        if (lane < 8) storec(bars + 640 + lane * 16, gen);
      }
      if (tid == 0) {
        while (loadc(bars + 640 + g * 16) < gen) __builtin_amdgcn_s_sleep(2);
      }
      __syncthreads();
    }
  }
}

extern "C" void kernel_launch(void* const* d_in, const int* in_sizes, int n_in, void* d_out,
                              int out_size, void* d_ws, size_t ws_size, hipStream_t stream) {
  const float* input = (const float*)d_in[0];
  const float* w1 = (const float*)d_in[1];
  const float* b1 = (const float*)d_in[2];
  const float* w2 = (const float*)d_in[3];
  const float* b2 = (const float*)d_in[4];
  const float* fcw = (const float*)d_in[5];
  const float* fcb = (const float*)d_in[6];

  float* out = (float*)d_out;
  float* pose = out;
  float* h1o = out + 768;
  float* c1o = h1o + 131072;
  float* h2o = c1o + 131072;
  float* c2o = h2o + 262144;

  uint_t* W = (uint_t*)d_ws;
  uint_t* i1a = W;             // in1 parity 0
  uint_t* i1b = W + I1U;       // in1 parity 1
  uint_t* i2a = W + 2 * I1U;   // in2 parity 0
  uint_t* i2b = i2a + I2U;     // in2 parity 1
  ushort_t* wp1 = (ushort_t*)(W + WP1U);
  ushort_t* wp2 = (ushort_t*)(W + WP2U);
  uint_t* bars = W + BARU;

  hipMemsetAsync(d_ws, 0, (size_t)EXU * 4, stream);  // exchange buffers (t=0 state)
  hipMemsetAsync(bars, 0, 8192, stream);             // barrier slots + flags
  pack_kernel<<<307, 256, 0, stream>>>(w1, w2, fcb, input, pose, wp1, wp2, i1a);

  persist<<<512, 256, 0, stream>>>(input, wp1, wp2, b1, b2, fcw, pose, h1o, c1o, h2o, c2o,
                                   i1a, i1b, i2a, i2b, bars);
}

// Round 7
// 7961.728 us; speedup vs baseline: 1.0815x; 1.0815x over previous
//
#include <hip/hip_runtime.h>

typedef _Float16 f16;
typedef _Float16 f16x8 __attribute__((ext_vector_type(8)));
typedef float f32x4 __attribute__((ext_vector_type(4)));
typedef unsigned short ushort_t;
typedef unsigned int uint_t;

// ---------------------------------------------------------------------------
// PoseConvLSTM persistent kernel, 129 phases.
// Grid 256 blocks x 512 threads (8 waves), 1 block/CU, full 256-VGPR budget
// (R5/R6 ran 2 blocks/CU at 128 VGPRs -> scratch spills -> 16.7 GB HBM writes;
// this config keeps all loop state in registers).
// Phase ph: layer1[t=ph] || layer2[t=ph-1]. Block = (tile 8x8 px, channel
// slice of 4). Wave = (m-tile, K-half); K-half partials merge via LDS.
// A (weights) split-f16 hi+lo (2 MFMA/product); B (states) f16 hi only.
// Exchange: tile-major [tile(64)][pair(C/2)][pix(64)] uints via relaxed
// agent-scope atomics (write-through, no wbl2/inv). c-states in registers.
// Barrier: R4-style relaxed fetch_add shards (outlier-free).
// d_out (floats): pose[768] | h1[131072] | c1[131072] | h2[262144] | c2[262144]
// ---------------------------------------------------------------------------

#define I1U 98304    // 64*24*64 uints per parity
#define I2U 196608   // 64*48*64
#define EXU 589824   // 2*(I1U+I2U)
#define WP1U 589824  // uint offset of wp1
#define WP2U 663552  // + 73728
#define BARU 884736  // uint offset of barrier region
#define NPH 129

__device__ __forceinline__ float sigm(float x) { return 1.0f / (1.0f + __expf(-x)); }
__device__ __forceinline__ ushort_t f2u(f16 v) { return __builtin_bit_cast(ushort_t, v); }
__device__ __forceinline__ f16x8 u2f(uint4 v) { return __builtin_bit_cast(f16x8, v); }
__device__ __forceinline__ uint_t loadc(const uint_t* p) {
  return __hip_atomic_load(p, __ATOMIC_RELAXED, __HIP_MEMORY_SCOPE_AGENT);
}
__device__ __forceinline__ void storec(uint_t* p, uint_t v) {
  __hip_atomic_store(p, v, __ATOMIC_RELAXED, __HIP_MEMORY_SCOPE_AGENT);
}

// ---- init: pack weights (hi/lo frag order); pose=fc_b; stage x[0] ----
__global__ __launch_bounds__(256) void pack_kernel(const float* __restrict__ w1,
                                                   const float* __restrict__ w2,
                                                   const float* __restrict__ fcb,
                                                   const float* __restrict__ x0,
                                                   float* __restrict__ pose,
                                                   ushort_t* __restrict__ wp1,
                                                   ushort_t* __restrict__ wp2,
                                                   uint_t* __restrict__ i1a) {
  int i = blockIdx.x * 256 + threadIdx.x;
  if (i < 55296) {  // wp2
    int lane = i & 63;
    int r0 = i >> 6;
    int hl = r0 & 1;
    int f = r0 >> 1;  // (mb*27+s)*8+mt
    int mt = f & 7;
    int sm = f >> 3;
    int s = sm % 27, mb = sm / 27;
    int m = mt * 16 + (lane & 15);
    int rg = mb * 128 + m;
    int h = rg >> 2, G = rg & 3;
    int orow = G * 64 + h;
    int tap = s / 3, cb = (s % 3) * 32;
    int cq = cb + (lane >> 4) * 8;
    for (int j = 0; j < 8; ++j) {
      float v = w2[(orow * 96 + cq + j) * 9 + tap];
      f16 vh = (f16)v;
      f16 vl = (f16)(v - (float)vh);
      wp2[(f * 2 + hl) * 512 + lane * 8 + j] = f2u(hl ? vl : vh);
    }
    return;
  }
  i -= 55296;
  if (i < 18432) {  // wp1: c<32 -> w1 ch c+3 (h1), c32-34 -> w1 ch c-32 (x), else 0
    int lane = i & 63;
    int r0 = i >> 6;
    int hl = r0 & 1;
    int f = r0 >> 1;  // (mb*18+s)*4+mt
    int mt = f & 3;
    int sm = f >> 2;
    int s = sm % 18, mb = sm / 18;
    int m = mt * 16 + (lane & 15);
    int rg = mb * 64 + m;
    int h = rg >> 2, G = rg & 3;
    int orow = G * 32 + h;
    int tap = s >> 1, cb = (s & 1) * 32;
    int cq = cb + (lane >> 4) * 8;
    for (int j = 0; j < 8; ++j) {
      int c = cq + j;
      float v = 0.f;
      if (c < 32) v = w1[(orow * 35 + (c + 3)) * 9 + tap];
      else if (c < 35) v = w1[(orow * 35 + (c - 32)) * 9 + tap];
      f16 vh = (f16)v;
      f16 vl = (f16)(v - (float)vh);
      wp1[(f * 2 + hl) * 512 + lane * 8 + j] = f2u(hl ? vl : vh);
    }
    return;
  }
  i -= 18432;
  if (i < 768) {
    pose[i] = fcb[i % 6];
    return;
  }
  i -= 768;
  if (i < 4096) {  // x[0] -> in1 parity0, tile-major pairs 16,17
    int y = i >> 6, x = i & 63;
    float v0 = x0[i], v1 = x0[4096 + i], v2 = x0[8192 + i];
    int tile = (y >> 3) * 8 + (x >> 3);
    int pit = (y & 7) * 8 + (x & 7);
    i1a[(tile * 24 + 16) * 64 + pit] = (uint_t)f2u((f16)v0) | ((uint_t)f2u((f16)v1) << 16);
    i1a[(tile * 24 + 17) * 64 + pit] = (uint_t)f2u((f16)v2);
  }
}

#define MFMA(a, b, c) __builtin_amdgcn_mfma_f32_16x16x32_f16((a), (b), (c), 0, 0, 0)

__global__ __launch_bounds__(512) void persist(
    const float* __restrict__ input, const ushort_t* __restrict__ wp1,
    const ushort_t* __restrict__ wp2, const float* __restrict__ b1g,
    const float* __restrict__ b2g, const float* __restrict__ fcw, float* __restrict__ pose,
    float* __restrict__ h1o, float* __restrict__ c1o, float* __restrict__ h2o,
    float* __restrict__ c2o, uint_t* i1x, uint_t* i1y, uint_t* i2x, uint_t* i2y,
    int* bars) {
  __shared__ __align__(16) ushort_t BH2[100 * 104];  // [pos][96ch + 8 pad] 20.8 KB
  __shared__ __align__(16) ushort_t BH1[100 * 72];   // [pos][64ch + 8 pad] 14.4 KB
  __shared__ float zs[16 * 4 * 64];                  // 16 KB K-half merge
  __shared__ float red[8][6];

  const int tid = threadIdx.x, blk = blockIdx.x;
  const int lane = tid & 63, w = tid >> 6;            // 8 waves
  const int q = lane >> 4, nl = lane & 15, py = nl >> 3, px = nl & 7;
  const int slice = blk & 3;                          // channel slice
  const int nc = blk >> 2;                            // 0..63 spatial tile
  const int Y0 = (nc >> 3) * 8, X0 = (nc & 7) * 8;
  const int mt = w & 3, kh = w >> 2;                  // L2 wave task
  const bool isL1w = (w < 4);
  const int mt1 = w & 1, kh1 = (w >> 1) & 1;          // L1 wave task (w<4)

  uint_t* i1[2] = {i1x, i1y};
  uint_t* i2[2] = {i2x, i2y};
  uint_t* uBH2 = (uint_t*)BH2;
  uint_t* uBH1 = (uint_t*)BH1;

  // A-frag base pointers
  const int mt2 = slice * 4 + mt;  // 0..15
  const int g1 = slice * 2 + mt1;  // 0..7
  const int s0_2 = kh ? 14 : 0, s1_2 = kh ? 27 : 14;
  const int s0_1 = kh1 ? 9 : 0, s1_1 = kh1 ? 18 : 9;
  const ushort_t* aB2 =
      wp2 + ((size_t)((mt2 >> 3) * 27 + s0_2) * 8 + (mt2 & 7)) * 1024 + lane * 8;
  const ushort_t* aB1 =
      wp1 + ((size_t)((g1 >> 2) * 18 + s0_1) * 4 + (g1 & 3)) * 1024 + lane * 8;

  int bO2[4], bO1[4];
#pragma unroll
  for (int nt = 0; nt < 4; ++nt) {
    bO2[nt] = ((nt * 2 + py) * 10 + px) * 104 + q * 8;
    bO1[nt] = ((nt * 2 + py) * 10 + px) * 72 + q * 8;
  }

  // ---- phase-invariant staging offsets (512 threads: 10 + 4 loads) ----
  int gO2[10], lO2[10];
  uint_t vm2 = 0;
#pragma unroll
  for (int k = 0; k < 10; ++k) {
    int i = tid + k * 512;
    if (i > 4799) i = 4799;
    int pair = i / 100, pos = i - pair * 100;
    int hy = pos / 10, hx = pos - hy * 10;
    int gy = Y0 + hy - 1, gx = X0 + hx - 1;
    if ((unsigned)gy < 64u && (unsigned)gx < 64u) vm2 |= (1u << k);
    int tile = ((gy & 63) >> 3) * 8 + ((gx & 63) >> 3);
    int pit = ((gy & 7) << 3) + (gx & 7);
    gO2[k] = (tile * 48 + pair) * 64 + pit;
    lO2[k] = pos * 52 + pair;
  }
  int gO1[4], lO1[4];
  uint_t vm1 = 0;
#pragma unroll
  for (int k = 0; k < 4; ++k) {
    int i = tid + k * 512;
    if (i > 1799) i = 1799;
    int pair = i / 100, pos = i - pair * 100;
    int hy = pos / 10, hx = pos - hy * 10;
    int gy = Y0 + hy - 1, gx = X0 + hx - 1;
    if ((unsigned)gy < 64u && (unsigned)gx < 64u) vm1 |= (1u << k);
    int tile = ((gy & 63) >> 3) * 8 + ((gx & 63) >> 3);
    int pit = ((gy & 7) << 3) + (gx & 7);
    gO1[k] = (tile * 24 + pair) * 64 + pit;
    lO1[k] = pos * 36 + pair;
  }
  // one-time zero of BH1 channels 36..63 (uints 18..31; never overwritten)
  for (int z = tid; z < 1400; z += 512) {
    int pos = z / 14, u = 18 + (z - (z / 14) * 14);
    uBH1[pos * 36 + u] = 0u;
  }

  // preload biases + fcw (cell ownership phase-invariant)
  const int h2ch = mt2 * 4 + q;   // slice*16 + mt*4 + q
  const int h1ch = g1 * 4 + q;    // slice*8 + mt1*4 + q
  float b2r[4], b1r[4], fwr[2][6];
  int cidx2[2], cidx1[2];
#pragma unroll
  for (int G = 0; G < 4; ++G) {
    b2r[G] = b2g[G * 64 + h2ch];
    b1r[G] = b1g[G * 32 + h1ch];
  }
#pragma unroll
  for (int j = 0; j < 2; ++j) {
    int y2 = Y0 + (kh * 2 + j) * 2 + py, x2 = X0 + px;
    cidx2[j] = h2ch * 4096 + y2 * 64 + x2;
    int y1 = Y0 + (kh1 * 2 + j) * 2 + py;
    cidx1[j] = h1ch * 4096 + y1 * 64 + x2;
#pragma unroll
    for (int jj = 0; jj < 6; ++jj) fwr[j][jj] = fcw[jj * 262144 + cidx2[j]];
  }

  float c2r[2] = {0.f, 0.f}, c1r[2] = {0.f, 0.f};

  for (int ph = 0; ph < NPH; ++ph) {
    const int t1 = ph, t2 = ph - 1;
    const int p = ph & 1, pn = p ^ 1;
    const bool doL2 = (t2 >= 0), doL1 = isL1w && (t1 < 128);

    // ---- batched staging (all loads in flight, then LDS writes) ----
    {
      const uint_t* s2 = i2[pn];
      uint_t v[10];
#pragma unroll
      for (int k = 0; k < 10; ++k) v[k] = loadc(s2 + gO2[k]);
#pragma unroll
      for (int k = 0; k < 10; ++k) uBH2[lO2[k]] = ((vm2 >> k) & 1) ? v[k] : 0u;
      const uint_t* s1 = i1[p];
      uint_t u[4];
#pragma unroll
      for (int k = 0; k < 4; ++k) u[k] = loadc(s1 + gO1[k]);
#pragma unroll
      for (int k = 0; k < 4; ++k) uBH1[lO1[k]] = ((vm1 >> k) & 1) ? u[k] : 0u;
    }
    __syncthreads();

    // ---- layer 2 K-loop: wave = (mt, kh), 4 n-tiles, K-half ----
    f32x4 acc[4] = {{0, 0, 0, 0}, {0, 0, 0, 0}, {0, 0, 0, 0}, {0, 0, 0, 0}};
    if (doL2) {
      uint4 Ahb[2], Alb[2], Bb[2][4];
      Ahb[0] = *(const uint4*)(aB2);
      Alb[0] = *(const uint4*)(aB2 + 512);
      Ahb[1] = *(const uint4*)(aB2 + 8192);
      Alb[1] = *(const uint4*)(aB2 + 8704);
      {
        int cc = s0_2 % 3, tt = s0_2 / 3;
        int d = (tt / 3) * 1040 + (tt % 3) * 104 + cc * 32;
#pragma unroll
        for (int nt = 0; nt < 4; ++nt) Bb[0][nt] = *(const uint4*)(&BH2[bO2[nt] + d]);
      }
      for (int s = s0_2, i = 0; s < s1_2; ++s, ++i) {
        uint4 ah = Ahb[i & 1], al = Alb[i & 1];
        uint4 b0 = Bb[i & 1][0], b1 = Bb[i & 1][1], b2 = Bb[i & 1][2], b3 = Bb[i & 1][3];
        if (s + 2 < s1_2) {
          Ahb[i & 1] = *(const uint4*)(aB2 + (size_t)(i + 2) * 8192);
          Alb[i & 1] = *(const uint4*)(aB2 + (size_t)(i + 2) * 8192 + 512);
        }
        if (s + 1 < s1_2) {
          int sn = s + 1;
          int cc = sn % 3, tt = sn / 3;
          int d = (tt / 3) * 1040 + (tt % 3) * 104 + cc * 32;
#pragma unroll
          for (int nt = 0; nt < 4; ++nt) Bb[(i + 1) & 1][nt] = *(const uint4*)(&BH2[bO2[nt] + d]);
        }
        f16x8 A_h = u2f(ah), A_l = u2f(al);
        f16x8 B0 = u2f(b0), B1 = u2f(b1), B2 = u2f(b2), B3 = u2f(b3);
        acc[0] = MFMA(A_h, B0, acc[0]); acc[0] = MFMA(A_l, B0, acc[0]);
        acc[1] = MFMA(A_h, B1, acc[1]); acc[1] = MFMA(A_l, B1, acc[1]);
        acc[2] = MFMA(A_h, B2, acc[2]); acc[2] = MFMA(A_l, B2, acc[2]);
        acc[3] = MFMA(A_h, B3, acc[3]); acc[3] = MFMA(A_l, B3, acc[3]);
      }
      int pub = (kh ^ 1) * 2;
#pragma unroll
      for (int j = 0; j < 2; ++j) {
        int slot = mt * 4 + pub + j;
#pragma unroll
        for (int i = 0; i < 4; ++i) zs[(slot * 4 + i) * 64 + lane] = acc[pub + j][i];
      }
    }
    __syncthreads();

    // ---- layer 2 merge + epilogue (wave finalizes nt = kh*2 + {0,1}) ----
    if (doL2) {
      uint_t* dst = i2[p];
      float p6[6] = {0, 0, 0, 0, 0, 0};
#pragma unroll
      for (int j = 0; j < 2; ++j) {
        int nt = kh * 2 + j;
        int slot = mt * 4 + nt;
        f32x4 a = acc[nt];
#pragma unroll
        for (int i = 0; i < 4; ++i) a[i] += zs[(slot * 4 + i) * 64 + lane];
        float zi = a[0] + b2r[0], zf = a[1] + b2r[1], zo = a[2] + b2r[2], zg = a[3] + b2r[3];
        float cn = sigm(zf) * c2r[j] + sigm(zi) * tanhf(zg);
        float hn = sigm(zo) * tanhf(cn);
        c2r[j] = cn;
#pragma unroll
        for (int jj = 0; jj < 6; ++jj) p6[jj] += hn * fwr[j][jj];
        if (t2 < 127) {
          ushort_t hv = f2u((f16)hn);
          uint_t pw = (uint_t)__shfl_xor((int)(uint_t)hv, 16, 64);
          if ((q & 1) == 0) {  // dense 64B run: 16 lanes x consecutive pix
            int d = (nc * 48 + 16 + (h2ch >> 1)) * 64 + nt * 16 + nl;
            storec(dst + d, (uint_t)hv | (pw << 16));
          }
        } else {
          c2o[cidx2[j]] = cn;
          h2o[cidx2[j]] = hn;
        }
      }
#pragma unroll
      for (int jj = 0; jj < 6; ++jj)
#pragma unroll
        for (int off = 32; off; off >>= 1) p6[jj] += __shfl_xor(p6[jj], off, 64);
      if (lane == 0)
#pragma unroll
        for (int jj = 0; jj < 6; ++jj) red[w][jj] = p6[jj];
    }

    // ---- layer 1 K-loop (waves 0-3: wave = (mt1, kh1)) ----
    f32x4 ac1[4] = {{0, 0, 0, 0}, {0, 0, 0, 0}, {0, 0, 0, 0}, {0, 0, 0, 0}};
    if (doL1) {
      uint4 Ahb[2], Alb[2], Bb[2][4];
      Ahb[0] = *(const uint4*)(aB1);
      Alb[0] = *(const uint4*)(aB1 + 512);
      Ahb[1] = *(const uint4*)(aB1 + 4096);
      Alb[1] = *(const uint4*)(aB1 + 4608);
      {
        int cc = s0_1 & 1, tap = s0_1 >> 1;
        int d = (tap / 3) * 720 + (tap % 3) * 72 + cc * 32;
#pragma unroll
        for (int nt = 0; nt < 4; ++nt) Bb[0][nt] = *(const uint4*)(&BH1[bO1[nt] + d]);
      }
      for (int s = s0_1, i = 0; s < s1_1; ++s, ++i) {
        uint4 ah = Ahb[i & 1], al = Alb[i & 1];
        uint4 b0 = Bb[i & 1][0], b1 = Bb[i & 1][1], b2 = Bb[i & 1][2], b3 = Bb[i & 1][3];
        if (s + 2 < s1_1) {
          Ahb[i & 1] = *(const uint4*)(aB1 + (size_t)(i + 2) * 4096);
          Alb[i & 1] = *(const uint4*)(aB1 + (size_t)(i + 2) * 4096 + 512);
        }
        if (s + 1 < s1_1) {
          int sn = s + 1;
          int cc = sn & 1, tap = sn >> 1;
          int d = (tap / 3) * 720 + (tap % 3) * 72 + cc * 32;
#pragma unroll
          for (int nt = 0; nt < 4; ++nt) Bb[(i + 1) & 1][nt] = *(const uint4*)(&BH1[bO1[nt] + d]);
        }
        f16x8 A_h = u2f(ah), A_l = u2f(al);
        f16x8 B0 = u2f(b0), B1 = u2f(b1), B2 = u2f(b2), B3 = u2f(b3);
        ac1[0] = MFMA(A_h, B0, ac1[0]); ac1[0] = MFMA(A_l, B0, ac1[0]);
        ac1[1] = MFMA(A_h, B1, ac1[1]); ac1[1] = MFMA(A_l, B1, ac1[1]);
        ac1[2] = MFMA(A_h, B2, ac1[2]); ac1[2] = MFMA(A_l, B2, ac1[2]);
        ac1[3] = MFMA(A_h, B3, ac1[3]); ac1[3] = MFMA(A_l, B3, ac1[3]);
      }
    }
    __syncthreads();  // zs reuse fence (L2 merge reads done)
    if (doL1) {
      int pub = (kh1 ^ 1) * 2;
#pragma unroll
      for (int j = 0; j < 2; ++j) {
        int slot = mt1 * 4 + pub + j;
#pragma unroll
        for (int i = 0; i < 4; ++i) zs[(slot * 4 + i) * 64 + lane] = ac1[pub + j][i];
      }
    }
    if (slice == 1 && t1 < 127 && tid < 64) {  // stage x[t+1] -> in1[pn] pairs 16,17
      const float* xn = input + (size_t)(t1 + 1) * 12288;
      int y = Y0 + (tid >> 3), x = X0 + (tid & 7);
      int gi = y * 64 + x;
      float v0 = xn[gi], v1 = xn[4096 + gi], v2 = xn[8192 + gi];
      uint_t* d1 = i1[pn];
      storec(d1 + (nc * 24 + 16) * 64 + tid, (uint_t)f2u((f16)v0) | ((uint_t)f2u((f16)v1) << 16));
      storec(d1 + (nc * 24 + 17) * 64 + tid, (uint_t)f2u((f16)v2));
    }
    __syncthreads();
    if (doL1) {
      uint_t* d2 = i2[p];
      uint_t* d1 = i1[pn];
#pragma unroll
      for (int j = 0; j < 2; ++j) {
        int nt = kh1 * 2 + j;
        int slot = mt1 * 4 + nt;
        f32x4 a = ac1[nt];
#pragma unroll
        for (int i = 0; i < 4; ++i) a[i] += zs[(slot * 4 + i) * 64 + lane];
        float zi = a[0] + b1r[0], zf = a[1] + b1r[1], zo = a[2] + b1r[2], zg = a[3] + b1r[3];
        float cn = sigm(zf) * c1r[j] + sigm(zi) * tanhf(zg);
        float hn = sigm(zo) * tanhf(cn);
        c1r[j] = cn;
        ushort_t hv = f2u((f16)hn);
        uint_t pw = (uint_t)__shfl_xor((int)(uint_t)hv, 16, 64);
        if ((q & 1) == 0) {
          uint_t wv = (uint_t)hv | (pw << 16);
          int pix = nt * 16 + nl;
          storec(d2 + (nc * 48 + (h1ch >> 1)) * 64 + pix, wv);  // h1 -> in2[p]
          if (t1 < 127) storec(d1 + (nc * 24 + (h1ch >> 1)) * 64 + pix, wv);
        }
        if (t1 == 127) {
          c1o[cidx1[j]] = cn;
          h1o[cidx1[j]] = hn;
        }
      }
    }

    // ---- drain, pose, fetch_add grid barrier (R4-style, outlier-free) ----
    asm volatile("s_waitcnt vmcnt(0)" ::: "memory");
    __syncthreads();
    if (doL2 && tid < 6) {
      float s6 = 0.f;
#pragma unroll
      for (int ww = 0; ww < 8; ++ww) s6 += red[ww][tid];
      atomicAdd(pose + t2 * 6 + tid, s6);
    }
    if (ph + 1 < NPH) {
      if (tid == 0) {
        int* sub = bars + (blk & 7) * 32;  // 8 shards x 32 blocks, 128B apart
        int v = __hip_atomic_fetch_add(sub, 1, __ATOMIC_RELAXED, __HIP_MEMORY_SCOPE_AGENT);
        if (v == (ph + 1) * 32 - 1) {
          int r = __hip_atomic_fetch_add(bars + 256, 1, __ATOMIC_RELAXED, __HIP_MEMORY_SCOPE_AGENT);
          if (r == (ph + 1) * 8 - 1)
            __hip_atomic_store(bars + 288, ph + 1, __ATOMIC_RELAXED, __HIP_MEMORY_SCOPE_AGENT);
        }
        while (__hip_atomic_load(bars + 288, __ATOMIC_RELAXED, __HIP_MEMORY_SCOPE_AGENT) <= ph)
          __builtin_amdgcn_s_sleep(2);
      }
      __syncthreads();
    }
  }
}

extern "C" void kernel_launch(void* const* d_in, const int* in_sizes, int n_in, void* d_out,
                              int out_size, void* d_ws, size_t ws_size, hipStream_t stream) {
  const float* input = (const float*)d_in[0];
  const float* w1 = (const float*)d_in[1];
  const float* b1 = (const float*)d_in[2];
  const float* w2 = (const float*)d_in[3];
  const float* b2 = (const float*)d_in[4];
  const float* fcw = (const float*)d_in[5];
  const float* fcb = (const float*)d_in[6];

  float* out = (float*)d_out;
  float* pose = out;
  float* h1o = out + 768;
  float* c1o = h1o + 131072;
  float* h2o = c1o + 131072;
  float* c2o = h2o + 262144;

  uint_t* W = (uint_t*)d_ws;
  uint_t* i1a = W;             // in1 parity 0
  uint_t* i1b = W + I1U;       // in1 parity 1
  uint_t* i2a = W + 2 * I1U;   // in2 parity 0
  uint_t* i2b = i2a + I2U;     // in2 parity 1
  ushort_t* wp1 = (ushort_t*)(W + WP1U);
  ushort_t* wp2 = (ushort_t*)(W + WP2U);
  int* bars = (int*)(W + BARU);

  hipMemsetAsync(d_ws, 0, (size_t)EXU * 4, stream);  // exchange buffers (t=0 state)
  hipMemsetAsync(bars, 0, 1280, stream);             // barrier counters + flag
  pack_kernel<<<307, 256, 0, stream>>>(w1, w2, fcb, input, pose, wp1, wp2, i1a);

  persist<<<256, 512, 0, stream>>>(input, wp1, wp2, b1, b2, fcw, pose, h1o, c1o, h2o, c2o,
                                   i1a, i1b, i2a, i2b, bars);
}